// Round 5
// baseline (321.791 us; speedup 1.0000x reference)
//
#include <hip/hip_runtime.h>
#include <float.h>
#include <math.h>

#define K_CODES 1024
#define ED 64
#define NTOK 131072
#define TM 128            // tokens per block
#define TK 128            // codes per tile
#define NTILE (K_CODES / TK)
#define BLK 128           // threads per block (2 waves)

// ---------------------------------------------------------------------------
// NUMERICS ARE FROZEN (round-2/4 passed, absmax 3.8e-6, 0 argmin flips):
//  - zsq / e_sq: numpy pairwise_sum n=64: 8 accumulators strided 8, plain
//    mul+add (no fma), combine ((r0+r1)+(r2+r3))+((r4+r5)+(r6+r7)).
//  - dot(z,e): single sequential fmaf chain over d=0..63 (BLAS order).
//  - d2 = fmaf(-2,dot,zsq) + e_sq  (one rounding each).
//  - argmin: first index wins (per-thread ascending scan; cross-thread
//    reduce lexicographic (value, index)).
// Do not reassociate any of these.
//
// Round-4 post-mortem: 8x8 thread-tile = 1.0 B/FMA LDS traffic -> LDS-pipe
// bound at ~164 us (measured 244, VALUBusy 65%). This version: 16x8 tile =
// 0.75 B/FMA (6 ds_read_b128 per 128 FMA), LDS floor ~123 us ~ VALU floor 109.
// ---------------------------------------------------------------------------

// pre: blocks 0..511 -> zsq[t]; block 512 -> e_sq + zero counts/sse
__global__ __launch_bounds__(256) void vq_pre(const float* __restrict__ z_e,
                                              const float* __restrict__ cb,
                                              float* __restrict__ zsq_g,
                                              float* __restrict__ e_sq,
                                              unsigned int* __restrict__ counts,
                                              float* __restrict__ sse)
{
#pragma clang fp contract(off)
    const int tid = threadIdx.x;
    if (blockIdx.x < NTOK / 256) {
        const int t = blockIdx.x * 256 + tid;
        const float4* zp = (const float4*)(z_e + (size_t)t * ED);
        float zr[ED];
#pragma unroll
        for (int i = 0; i < 16; ++i) {
            float4 v = zp[i];
            zr[4 * i + 0] = v.x; zr[4 * i + 1] = v.y;
            zr[4 * i + 2] = v.z; zr[4 * i + 3] = v.w;
        }
        float r[8];
#pragma unroll
        for (int j = 0; j < 8; ++j) r[j] = zr[j] * zr[j];
#pragma unroll
        for (int i = 8; i < ED; i += 8)
#pragma unroll
            for (int j = 0; j < 8; ++j) r[j] = r[j] + zr[i + j] * zr[i + j];
        zsq_g[t] = ((r[0] + r[1]) + (r[2] + r[3])) + ((r[4] + r[5]) + (r[6] + r[7]));
    } else {
#pragma unroll
        for (int q = 0; q < 4; ++q) {
            const int k = tid * 4 + q;
            const float* e = cb + k * ED;
            float r[8];
#pragma unroll
            for (int j = 0; j < 8; ++j) r[j] = e[j] * e[j];
#pragma unroll
            for (int i = 8; i < ED; i += 8)
#pragma unroll
                for (int j = 0; j < 8; ++j) r[j] = r[j] + e[i + j] * e[i + j];
            e_sq[k] = ((r[0] + r[1]) + (r[2] + r[3])) + ((r[4] + r[5]) + (r[6] + r[7]));
            counts[k] = 0u;
        }
        if (tid == 0) *sse = 0.f;
    }
}

// ---------------------------------------------------------------------------
// main: 128 threads, 128 tokens x 1024 codes (8 tiles of 128).
// Thread (tx,ty): 16 tokens x 8 codes; per d-step 6x ds_read_b128 -> 128 fmaf.
// ---------------------------------------------------------------------------
__global__ __launch_bounds__(BLK, 1) void vq_main(const float* __restrict__ z_e,
                                                  const float* __restrict__ cb,
                                                  const float* __restrict__ e_sq,
                                                  const float* __restrict__ zsq_g,
                                                  float* __restrict__ out_zq,
                                                  float* __restrict__ out_idx,
                                                  unsigned int* __restrict__ counts,
                                                  float* __restrict__ sse)
{
#pragma clang fp contract(off)
    __shared__ float zT[ED * TM];          // zT[d*128+t]  32 KB
    __shared__ float eT[ED * TK];          // eT[d*128+c]  32 KB (reused as redbuf)
    __shared__ float zsqs[TM];
    __shared__ float esqs[TK];
    __shared__ unsigned int hist[K_CODES];
    __shared__ float wsum[2];

    const int tid = threadIdx.x;           // 0..127
    const int tx = tid & 15;               // code dim (16) -> 8 codes each
    const int ty = tid >> 4;               // token dim (8) -> 16 tokens each
    const int B0 = blockIdx.x * TM;

    for (int i = tid; i < K_CODES; i += BLK) hist[i] = 0u;

    // ---- stage zT (transpose): one token per thread ----
    {
        const float4* src = (const float4*)(z_e + (size_t)(B0 + tid) * ED);
#pragma unroll
        for (int j = 0; j < 16; ++j) {
            float4 v = src[j];
            const int d = 4 * j;
            zT[(d + 0) * TM + tid] = v.x;
            zT[(d + 1) * TM + tid] = v.y;
            zT[(d + 2) * TM + tid] = v.z;
            zT[(d + 3) * TM + tid] = v.w;
        }
        zsqs[tid] = zsq_g[B0 + tid];
    }

    float bestv[16];
    int   besti[16];
#pragma unroll
    for (int m = 0; m < 16; ++m) { bestv[m] = FLT_MAX; besti[m] = 0; }

    for (int tile = 0; tile < NTILE; ++tile) {
        __syncthreads();   // eT safe to overwrite; also covers zT/zsqs (tile 0)
        // ---- stage eT (transpose): one code per thread ----
        {
            const float4* src = (const float4*)(cb + (size_t)(tile * TK + tid) * ED);
#pragma unroll
            for (int j = 0; j < 16; ++j) {
                float4 v = src[j];
                const int d = 4 * j;
                eT[(d + 0) * TK + tid] = v.x;
                eT[(d + 1) * TK + tid] = v.y;
                eT[(d + 2) * TK + tid] = v.z;
                eT[(d + 3) * TK + tid] = v.w;
            }
            esqs[tid] = e_sq[tile * TK + tid];
        }
        __syncthreads();

        // ---- 16x8 register-tile GEMM over d ----
        float acc[16][8];
#pragma unroll
        for (int m = 0; m < 16; ++m)
#pragma unroll
            for (int n = 0; n < 8; ++n) acc[m][n] = 0.f;

#pragma unroll 8
        for (int d = 0; d < ED; ++d) {
            const float4 za = *(const float4*)&zT[d * TM + ty * 16];
            const float4 zb = *(const float4*)&zT[d * TM + ty * 16 + 4];
            const float4 zc = *(const float4*)&zT[d * TM + ty * 16 + 8];
            const float4 zd = *(const float4*)&zT[d * TM + ty * 16 + 12];
            const float4 ea = *(const float4*)&eT[d * TK + tx * 4];
            const float4 eb = *(const float4*)&eT[d * TK + 64 + tx * 4];
            float zf[16] = {za.x, za.y, za.z, za.w, zb.x, zb.y, zb.z, zb.w,
                            zc.x, zc.y, zc.z, zc.w, zd.x, zd.y, zd.z, zd.w};
            float ef[8]  = {ea.x, ea.y, ea.z, ea.w, eb.x, eb.y, eb.z, eb.w};
#pragma unroll
            for (int m = 0; m < 16; ++m)
#pragma unroll
                for (int n = 0; n < 8; ++n)
                    acc[m][n] = fmaf(zf[m], ef[n], acc[m][n]);
        }

        // ---- tile epilogue: d2 + running argmin (codes ascending per thread)
#pragma unroll
        for (int m = 0; m < 16; ++m) {
            const float zq = zsqs[ty * 16 + m];
#pragma unroll
            for (int n = 0; n < 8; ++n) {
                const int cl = (n < 4) ? (tx * 4 + n) : (64 + tx * 4 + (n - 4));
                const float d2 = fmaf(-2.f, acc[m][n], zq) + esqs[cl];
                if (d2 < bestv[m]) { bestv[m] = d2; besti[m] = tile * TK + cl; }
            }
        }
    }

    // ---- cross-thread (tx) argmin reduce via redbuf (reuse eT) ----
    __syncthreads();                       // all d-loop readers of eT done
    float* red_v = eT;                     // [TM][16]
    int*   red_i = (int*)&eT[TM * 16];     // [TM][16]
#pragma unroll
    for (int m = 0; m < 16; ++m) {
        red_v[(ty * 16 + m) * 16 + tx] = bestv[m];
        red_i[(ty * 16 + m) * 16 + tx] = besti[m];
    }
    __syncthreads();

    // ---- per-token final (one token per thread) ----
    float lsse = 0.f;
    {
        const int t = tid;
        float bv = red_v[t * 16 + 0];
        int   bi = red_i[t * 16 + 0];
#pragma unroll
        for (int x = 1; x < 16; ++x) {
            const float v = red_v[t * 16 + x];
            const int   i = red_i[t * 16 + x];
            if (v < bv || (v == bv && i < bi)) { bv = v; bi = i; }
        }
        atomicAdd(&hist[bi], 1u);
        out_idx[B0 + t] = (float)bi;

        // gather selected code, write z_q, SSE (frozen fmaf chain, d order)
        const float4* eq = (const float4*)(cb + (size_t)bi * ED);
        float4* oz = (float4*)(out_zq + (size_t)(B0 + t) * ED);
#pragma unroll
        for (int i = 0; i < 16; ++i) {
            float4 q = eq[i];
            oz[i] = q;
            const int d = 4 * i;
            float dx = q.x - zT[(d + 0) * TM + t]; lsse = fmaf(dx, dx, lsse);
            float dy = q.y - zT[(d + 1) * TM + t]; lsse = fmaf(dy, dy, lsse);
            float dz = q.z - zT[(d + 2) * TM + t]; lsse = fmaf(dz, dz, lsse);
            float dw = q.w - zT[(d + 3) * TM + t]; lsse = fmaf(dw, dw, lsse);
        }
    }

    // block SSE reduce: wave64 shfl then 2 waves -> one atomic
#pragma unroll
    for (int off = 32; off > 0; off >>= 1)
        lsse += __shfl_down(lsse, off, 64);
    const int lane = tid & 63, wid = tid >> 6;
    if (lane == 0) wsum[wid] = lsse;
    __syncthreads();
    if (tid == 0)
        atomicAdd(sse, wsum[0] + wsum[1]);

    // flush histogram
    for (int i = tid; i < K_CODES; i += BLK) {
        const unsigned int c = hist[i];
        if (c) atomicAdd(&counts[i], c);
    }
}

// ---------------------------------------------------------------------------
// final: entropy / losses scalars
// ---------------------------------------------------------------------------
__global__ __launch_bounds__(1024) void vq_final(const unsigned int* __restrict__ counts,
                                                 const float* __restrict__ sse,
                                                 float* __restrict__ out_sc)
{
    __shared__ float red[1024];
    const int i = threadIdx.x;
    const float c = (float)counts[i];
    const float p = c / (float)NTOK + 1e-10f;
    red[i] = p * logf(p);
    __syncthreads();
    for (int s = 512; s > 0; s >>= 1) {
        if (i < s) red[i] += red[i + s];
        __syncthreads();
    }
    if (i == 0) {
        const float entropy = -red[0];
        const float cbl = (*sse) / ((float)NTOK * (float)ED);
        out_sc[0] = cbl;                                   // codebook_loss
        out_sc[1] = 0.25f * cbl;                           // commitment_loss
        out_sc[2] = -0.1f * (entropy / 6.93147180559945f); // entropy_loss
        out_sc[3] = expf(entropy);                         // perplexity
    }
}

// ---------------------------------------------------------------------------
extern "C" void kernel_launch(void* const* d_in, const int* in_sizes, int n_in,
                              void* d_out, int out_size, void* d_ws, size_t ws_size,
                              hipStream_t stream)
{
    const float* z_e = (const float*)d_in[0];
    const float* cb  = (const float*)d_in[1];

    float* out   = (float*)d_out;
    float* o_zq  = out;                              // [131072,64]
    float* o_idx = out + (size_t)NTOK * ED;          // [131072] (as float)
    float* o_sc  = o_idx + NTOK;                     // 4 scalars

    float*        e_sq   = (float*)d_ws;                          // 4 KB
    unsigned int* counts = (unsigned int*)((char*)d_ws + 4096);   // 4 KB
    float*        sse    = (float*)((char*)d_ws + 8192);          // 4 B
    float*        zsq_g  = (float*)((char*)d_ws + 12288);         // 512 KB

    vq_pre  <<<NTOK / 256 + 1, 256, 0, stream>>>(z_e, cb, zsq_g, e_sq, counts, sse);
    vq_main <<<NTOK / TM, BLK, 0, stream>>>(z_e, cb, e_sq, zsq_g,
                                            o_zq, o_idx, counts, sse);
    vq_final<<<1, 1024, 0, stream>>>(counts, sse, o_sc);
}

// Round 6
// 237.177 us; speedup vs baseline: 1.3568x; 1.3568x over previous
//
#include <hip/hip_runtime.h>
#include <float.h>
#include <math.h>

#define K_CODES 1024
#define ED 64
#define NTOK 131072
#define EPS 4e-4f   // flag band; total approx-vs-exact-chain bound ~7e-5 -> 6x margin

typedef __attribute__((ext_vector_type(8)))  short short8;   // 8 bf16 (4 VGPRs)
typedef __attribute__((ext_vector_type(16))) float float16;  // MFMA 32x32 acc

// ---------------------------------------------------------------------------
// NUMERICS OF THE EXACT PATH ARE FROZEN (rounds 2/4/5 passed, 0 argmin flips):
//  - zsq / e_sq: numpy pairwise_sum n=64 (8 accs strided 8, mul+add no fma,
//    combine ((r0+r1)+(r2+r3))+((r4+r5)+(r6+r7))), contract(off).
//  - dot(z,e): single sequential fmaf chain over d=0..63.
//  - d2 = fmaf(-2,dot,zsq) + e_sq.
//  - argmin: first index wins (lexicographic (value,index) updates).
// Phase 1 (MFMA bf16 hi/lo) is APPROXIMATE and only selects candidate tiles;
// phase 2 rescores candidates with the frozen chain -> bit-identical indices.
// ---------------------------------------------------------------------------

static __device__ __forceinline__ unsigned short f2bf(float x) {  // RNE
    unsigned u = __float_as_uint(x);
    u += 0x7fffu + ((u >> 16) & 1u);
    return (unsigned short)(u >> 16);
}
static __device__ __forceinline__ float bf2f(unsigned short h) {
    return __uint_as_float(((unsigned)h) << 16);
}

// ---------------------------------------------------------------------------
// pre: blocks 0..511 tokens (zsq + z bf16-split fragments);
//      blocks 512..515 codes (e_sq + e bf16-split fragments, zero counts/sse).
// Fragment layout (16B short8 units), matching MFMA A/B lane order
//   A[m=lane&31][k=(lane>>5)*8+j], B[k][n=lane&31] same k split:
//   frag[(row32tile*8 + g)*32 + (row&31)], g = (d/8) = q*2+h, d = g*8+j.
// ---------------------------------------------------------------------------
__global__ __launch_bounds__(256) void vq_pre(const float* __restrict__ z_e,
                                              const float* __restrict__ cb,
                                              float* __restrict__ zsq_g,
                                              short8* __restrict__ zfH,
                                              short8* __restrict__ zfL,
                                              float* __restrict__ e_sq,
                                              short8* __restrict__ efH,
                                              short8* __restrict__ efL,
                                              unsigned int* __restrict__ counts,
                                              float* __restrict__ sse)
{
#pragma clang fp contract(off)
    const int tid = threadIdx.x;
    if (blockIdx.x < NTOK / 256) {
        const int t = blockIdx.x * 256 + tid;
        const float4* zp = (const float4*)(z_e + (size_t)t * ED);
        const int n = t & 31, tt = t >> 5;
        float r[8];
#pragma unroll
        for (int g = 0; g < 8; ++g) {
            float4 a = zp[2 * g], b = zp[2 * g + 1];
            float v[8] = {a.x, a.y, a.z, a.w, b.x, b.y, b.z, b.w};
            short8 hv, lv;
#pragma unroll
            for (int j = 0; j < 8; ++j) {
                unsigned short hb = f2bf(v[j]);
                hv[j] = (short)hb;
                lv[j] = (short)f2bf(v[j] - bf2f(hb));
                const float sq = v[j] * v[j];          // frozen pairwise zsq
                r[j] = g ? (r[j] + sq) : sq;
            }
            zfH[(tt * 8 + g) * 32 + n] = hv;
            zfL[(tt * 8 + g) * 32 + n] = lv;
        }
        zsq_g[t] = ((r[0] + r[1]) + (r[2] + r[3])) + ((r[4] + r[5]) + (r[6] + r[7]));
    } else {
        const int k = (blockIdx.x - NTOK / 256) * 256 + tid;   // 0..1023
        const float4* ep = (const float4*)(cb + (size_t)k * ED);
        const int m = k & 31, ct = k >> 5;
        float r[8];
#pragma unroll
        for (int g = 0; g < 8; ++g) {
            float4 a = ep[2 * g], b = ep[2 * g + 1];
            float v[8] = {a.x, a.y, a.z, a.w, b.x, b.y, b.z, b.w};
            short8 hv, lv;
#pragma unroll
            for (int j = 0; j < 8; ++j) {
                unsigned short hb = f2bf(v[j]);
                hv[j] = (short)hb;
                lv[j] = (short)f2bf(v[j] - bf2f(hb));
                const float sq = v[j] * v[j];          // frozen pairwise e_sq
                r[j] = g ? (r[j] + sq) : sq;
            }
            efH[(ct * 8 + g) * 32 + m] = hv;
            efL[(ct * 8 + g) * 32 + m] = lv;
        }
        e_sq[k] = ((r[0] + r[1]) + (r[2] + r[3])) + ((r[4] + r[5]) + (r[6] + r[7]));
        counts[k] = 0u;
        if (k == 0) *sse = 0.f;
    }
}

// ---------------------------------------------------------------------------
// phase 1: approx scores via bf16 MFMA (3 products: hh, h*l, l*h).
// Wave owns 64 codes (2 x 32-code m-tiles, A-frags in regs); block = 4 waves
// = 256 codes; blockIdx.y = code group (4); blockIdx.x = 8-token-tile chunk.
// Per (token,32-code-tile) store: tA = -2*max(dot) with argmin-in-tile packed
// into low 5 mantissa bits (<=31 ulp perturbation << EPS); tB = -2*secondmax.
// ---------------------------------------------------------------------------
__global__ __launch_bounds__(256, 2) void vq_approx(const short8* __restrict__ zfH,
                                                    const short8* __restrict__ zfL,
                                                    const short8* __restrict__ efH,
                                                    const short8* __restrict__ efL,
                                                    float* __restrict__ tA,
                                                    float* __restrict__ tB)
{
    const int tid = threadIdx.x;
    const int lane = tid & 63, wv = tid >> 6;
    const int h = lane >> 5, ml = lane & 31;
    const int ct0 = blockIdx.y * 8 + wv * 2;       // wave's two 32-code tiles

    short8 ea[2][4], eb[2][4];                     // A-frags: eh, el (in regs)
#pragma unroll
    for (int mt = 0; mt < 2; ++mt) {
        const int ct = ct0 + mt;
#pragma unroll
        for (int q = 0; q < 4; ++q) {
            const int idx = (ct * 8 + q * 2 + h) * 32 + ml;
            ea[mt][q] = efH[idx];
            eb[mt][q] = efL[idx];
        }
    }

    const int tt0 = blockIdx.x * 8;
    for (int it = 0; it < 8; ++it) {
        const int tt = tt0 + it;
        short8 zh[4], zl[4];
#pragma unroll
        for (int q = 0; q < 4; ++q) {
            const int idx = (tt * 8 + q * 2 + h) * 32 + ml;
            zh[q] = zfH[idx];
            zl[q] = zfL[idx];
        }
        float16 acc0 = {}, acc1 = {};
#pragma unroll
        for (int q = 0; q < 4; ++q) {
            acc0 = __builtin_amdgcn_mfma_f32_32x32x16_bf16(ea[0][q], zh[q], acc0, 0, 0, 0);
            acc1 = __builtin_amdgcn_mfma_f32_32x32x16_bf16(ea[1][q], zh[q], acc1, 0, 0, 0);
            acc0 = __builtin_amdgcn_mfma_f32_32x32x16_bf16(ea[0][q], zl[q], acc0, 0, 0, 0);
            acc1 = __builtin_amdgcn_mfma_f32_32x32x16_bf16(ea[1][q], zl[q], acc1, 0, 0, 0);
            acc0 = __builtin_amdgcn_mfma_f32_32x32x16_bf16(eb[0][q], zh[q], acc0, 0, 0, 0);
            acc1 = __builtin_amdgcn_mfma_f32_32x32x16_bf16(eb[1][q], zh[q], acc1, 0, 0, 0);
        }
        // epilogue: per m-tile (32 codes) track (max dot, its row, 2nd max)
#pragma unroll
        for (int mt = 0; mt < 2; ++mt) {
            const float16 acc = mt ? acc1 : acc0;
            float v1 = -FLT_MAX, v2 = -FLT_MAX;
            int i1 = 0;
#pragma unroll
            for (int rg = 0; rg < 16; ++rg) {
                const float v = acc[rg];
                const int mrow = (rg & 3) + 8 * (rg >> 2) + 4 * h;  // C/D row (m74/m101)
                if (v > v1) { v2 = v1; v1 = v; i1 = mrow; }
                else v2 = fmaxf(v2, v);
            }
            const float o1 = __shfl_xor(v1, 32);
            const float o2 = __shfl_xor(v2, 32);
            const int   oi = __shfl_xor(i1, 32);
            const float lo = fminf(v1, o1);
            if (o1 > v1) { v1 = o1; i1 = oi; }
            v2 = fmaxf(lo, fmaxf(v2, o2));          // exact 2nd-largest merge
            if (lane < 32) {
                const int t = tt * 32 + lane;        // C/D col = token
                const unsigned bits = (__float_as_uint(-2.f * v1) & ~31u) | (unsigned)i1;
                tA[(size_t)(ct0 + mt) * NTOK + t] = __uint_as_float(bits);
                tB[(size_t)(ct0 + mt) * NTOK + t] = -2.f * v2;
            }
        }
    }
}

// ---------------------------------------------------------------------------
// phase 2: exact rescore of candidates (frozen chain) + fused epilogue.
// ---------------------------------------------------------------------------
__global__ __launch_bounds__(256) void vq_exact(const float* __restrict__ z_e,
                                                const float* __restrict__ cb,
                                                const float* __restrict__ e_sq,
                                                const float* __restrict__ zsq_g,
                                                const float* __restrict__ tA,
                                                const float* __restrict__ tB,
                                                float* __restrict__ out_zq,
                                                float* __restrict__ out_idx,
                                                unsigned int* __restrict__ counts,
                                                float* __restrict__ sse)
{
#pragma clang fp contract(off)
    __shared__ unsigned int hist[K_CODES];
    __shared__ float wsum[4];
    const int tid = threadIdx.x;
    for (int i = tid; i < K_CODES; i += 256) hist[i] = 0u;
    __syncthreads();

    const int t = blockIdx.x * 256 + tid;

    float m = FLT_MAX;
#pragma unroll
    for (int ct = 0; ct < 32; ++ct)
        m = fminf(m, tA[(size_t)ct * NTOK + t]);
    const float thr = m + EPS;

    const float4* zp = (const float4*)(z_e + (size_t)t * ED);
    float zr[ED];
#pragma unroll
    for (int i = 0; i < 16; ++i) {
        float4 v = zp[i];
        zr[4 * i + 0] = v.x; zr[4 * i + 1] = v.y;
        zr[4 * i + 2] = v.z; zr[4 * i + 3] = v.w;
    }
    const float zsq = zsq_g[t];

    int cand[8];
    int cnt = 0;
    unsigned fullmask = 0;
    for (int ct = 0; ct < 32; ++ct) {
        const float a = tA[(size_t)ct * NTOK + t];
        if (a <= thr) {
            if (cnt < 8) cand[cnt++] = ct * 32 + (int)(__float_as_uint(a) & 31u);
            else fullmask |= (1u << ct);             // overflow -> full scan (never in practice)
            if (tB[(size_t)ct * NTOK + t] <= thr) fullmask |= (1u << ct);  // tie/rival in tile
        }
    }

    float best = FLT_MAX;
    int bi = 0;
    // wave-uniform candidate loop (cnt >= 1 always: min's own tile is flagged)
    for (int i = 0; __any(i < cnt); ++i) {
        const bool act = (i < cnt);
        const int c = act ? cand[i] : cand[0];
        const float* __restrict__ e = cb + (size_t)c * ED;
        float a = 0.f;
#pragma unroll
        for (int d = 0; d < ED; ++d) a = fmaf(zr[d], e[d], a);   // frozen chain
        const float d2 = fmaf(-2.f, a, zsq) + e_sq[c];
        if (act && (d2 < best || (d2 == best && c < bi))) { best = d2; bi = c; }
    }
    // rare full-tile scans (ties / multiple in-band rivals)
    while (__any(fullmask != 0)) {
        const bool act = (fullmask != 0);
        const int ct = act ? (__ffs(fullmask) - 1) : 0;
        if (act) fullmask &= fullmask - 1;
        for (int j = 0; j < 32; ++j) {
            const int c = ct * 32 + j;
            const float* __restrict__ e = cb + (size_t)c * ED;
            float a = 0.f;
#pragma unroll
            for (int d = 0; d < ED; ++d) a = fmaf(zr[d], e[d], a);
            const float d2 = fmaf(-2.f, a, zsq) + e_sq[c];
            if (act && (d2 < best || (d2 == best && c < bi))) { best = d2; bi = c; }
        }
    }

    atomicAdd(&hist[bi], 1u);
    out_idx[t] = (float)bi;

    // gather selected code, write z_q, SSE (frozen fmaf chain, d order)
    const float4* eq = (const float4*)(cb + (size_t)bi * ED);
    float4* oz = (float4*)(out_zq + (size_t)t * ED);
    float lsse = 0.f;
#pragma unroll
    for (int i = 0; i < 16; ++i) {
        float4 q = eq[i];
        oz[i] = q;
        float dx = q.x - zr[4 * i + 0]; lsse = fmaf(dx, dx, lsse);
        float dy = q.y - zr[4 * i + 1]; lsse = fmaf(dy, dy, lsse);
        float dz = q.z - zr[4 * i + 2]; lsse = fmaf(dz, dz, lsse);
        float dw = q.w - zr[4 * i + 3]; lsse = fmaf(dw, dw, lsse);
    }
#pragma unroll
    for (int off = 32; off > 0; off >>= 1)
        lsse += __shfl_down(lsse, off, 64);
    const int lane = tid & 63, wid = tid >> 6;
    if (lane == 0) wsum[wid] = lsse;
    __syncthreads();
    if (tid == 0)
        atomicAdd(sse, (wsum[0] + wsum[1]) + (wsum[2] + wsum[3]));
    for (int i = tid; i < K_CODES; i += 256) {
        const unsigned int c = hist[i];
        if (c) atomicAdd(&counts[i], c);
    }
}

// ---------------------------------------------------------------------------
// final: entropy / losses scalars
// ---------------------------------------------------------------------------
__global__ __launch_bounds__(1024) void vq_final(const unsigned int* __restrict__ counts,
                                                 const float* __restrict__ sse,
                                                 float* __restrict__ out_sc)
{
    __shared__ float red[1024];
    const int i = threadIdx.x;
    const float c = (float)counts[i];
    const float p = c / (float)NTOK + 1e-10f;
    red[i] = p * logf(p);
    __syncthreads();
    for (int s = 512; s > 0; s >>= 1) {
        if (i < s) red[i] += red[i + s];
        __syncthreads();
    }
    if (i == 0) {
        const float entropy = -red[0];
        const float cbl = (*sse) / ((float)NTOK * (float)ED);
        out_sc[0] = cbl;                                   // codebook_loss
        out_sc[1] = 0.25f * cbl;                           // commitment_loss
        out_sc[2] = -0.1f * (entropy / 6.93147180559945f); // entropy_loss
        out_sc[3] = expf(entropy);                         // perplexity
    }
}

// ---------------------------------------------------------------------------
extern "C" void kernel_launch(void* const* d_in, const int* in_sizes, int n_in,
                              void* d_out, int out_size, void* d_ws, size_t ws_size,
                              hipStream_t stream)
{
    const float* z_e = (const float*)d_in[0];
    const float* cb  = (const float*)d_in[1];

    float* out   = (float*)d_out;
    float* o_zq  = out;                              // [131072,64]
    float* o_idx = out + (size_t)NTOK * ED;          // [131072] (as float)
    float* o_sc  = o_idx + NTOK;                     // 4 scalars

    char* ws = (char*)d_ws;
    float*        e_sq   = (float*)(ws);                     // 4 KB
    unsigned int* counts = (unsigned int*)(ws + 4096);       // 4 KB
    float*        sse    = (float*)(ws + 8192);              // 4 B
    float*        zsq_g  = (float*)(ws + 8448);              // 512 KB
    short8*       efH    = (short8*)(ws + 532736);           // 128 KB
    short8*       efL    = (short8*)(ws + 663808);           // 128 KB
    short8*       zfH    = (short8*)(ws + (1u << 20));       // 16 MB
    short8*       zfL    = (short8*)(ws + 17825792);         // 16 MB
    float*        tA     = (float*)(ws + 34603008);          // 16 MB
    float*        tB     = (float*)(ws + 51380224);          // 16 MB (end 64 MB)

    vq_pre   <<<NTOK / 256 + 4, 256, 0, stream>>>(z_e, cb, zsq_g, zfH, zfL,
                                                  e_sq, efH, efL, counts, sse);
    vq_approx<<<dim3(NTOK / 256, 4), 256, 0, stream>>>(zfH, zfL, efH, efL, tA, tB);
    vq_exact <<<NTOK / 256, 256, 0, stream>>>(z_e, cb, e_sq, zsq_g, tA, tB,
                                              o_zq, o_idx, counts, sse);
    vq_final <<<1, 1024, 0, stream>>>(counts, sse, o_sc);
}

// Round 7
// 224.032 us; speedup vs baseline: 1.4364x; 1.0587x over previous
//
#include <hip/hip_runtime.h>
#include <float.h>
#include <math.h>

#define K_CODES 1024
#define ED 64
#define NTOK 131072
#define EPS 4e-4f   // flag band; approx-vs-exact bound ~7e-5 -> 6x margin

typedef __attribute__((ext_vector_type(8)))  short short8;   // 8 bf16 (4 VGPRs)
typedef __attribute__((ext_vector_type(16))) float float16;  // MFMA 32x32 acc

// ---------------------------------------------------------------------------
// NUMERICS OF THE EXACT PATH ARE FROZEN (rounds 2/4/5/6 passed, 0 flips):
//  - zsq / e_sq: numpy pairwise_sum n=64 (8 accs strided 8, mul+add no fma,
//    combine ((r0+r1)+(r2+r3))+((r4+r5)+(r6+r7))), contract(off).
//  - dot(z,e): single sequential fmaf chain over d=0..63.
//  - d2 = fmaf(-2,dot,zsq) + e_sq.
//  - argmin: first index wins (lexicographic (value,index) updates).
// Phase 1 (MFMA bf16 hi/lo) only selects candidates; tokens with a single
// in-band candidate and no in-band rival take it WITHOUT rescoring (band
// proof: all other codes are > EPS - 2*approx_err - esq_spread away).
// Exact ties inside a tile force tB==tA -> fullmask -> full 32-scan.
// ---------------------------------------------------------------------------

static __device__ __forceinline__ unsigned short f2bf(float x) {  // RNE
    unsigned u = __float_as_uint(x);
    u += 0x7fffu + ((u >> 16) & 1u);
    return (unsigned short)(u >> 16);
}
static __device__ __forceinline__ float bf2f(unsigned short h) {
    return __uint_as_float(((unsigned)h) << 16);
}

// ---------------------------------------------------------------------------
// pre: blocks 0..511 tokens (zsq + z bf16-split fragments);
//      blocks 512..515 codes (e_sq + e bf16-split frags, zero counts/sse).
// frag[(row32tile*8 + g)*32 + (row&31)], g = d/8, lane k-half h = g&1.
// ---------------------------------------------------------------------------
__global__ __launch_bounds__(256) void vq_pre(const float* __restrict__ z_e,
                                              const float* __restrict__ cb,
                                              float* __restrict__ zsq_g,
                                              short8* __restrict__ zfH,
                                              short8* __restrict__ zfL,
                                              float* __restrict__ e_sq,
                                              short8* __restrict__ efH,
                                              short8* __restrict__ efL,
                                              unsigned int* __restrict__ counts,
                                              float* __restrict__ sse)
{
#pragma clang fp contract(off)
    const int tid = threadIdx.x;
    if (blockIdx.x < NTOK / 256) {
        const int t = blockIdx.x * 256 + tid;
        const float4* zp = (const float4*)(z_e + (size_t)t * ED);
        const int n = t & 31, tt = t >> 5;
        float r[8];
#pragma unroll
        for (int g = 0; g < 8; ++g) {
            float4 a = zp[2 * g], b = zp[2 * g + 1];
            float v[8] = {a.x, a.y, a.z, a.w, b.x, b.y, b.z, b.w};
            short8 hv, lv;
#pragma unroll
            for (int j = 0; j < 8; ++j) {
                unsigned short hb = f2bf(v[j]);
                hv[j] = (short)hb;
                lv[j] = (short)f2bf(v[j] - bf2f(hb));
                const float sq = v[j] * v[j];          // frozen pairwise zsq
                r[j] = g ? (r[j] + sq) : sq;
            }
            zfH[(tt * 8 + g) * 32 + n] = hv;
            zfL[(tt * 8 + g) * 32 + n] = lv;
        }
        zsq_g[t] = ((r[0] + r[1]) + (r[2] + r[3])) + ((r[4] + r[5]) + (r[6] + r[7]));
    } else {
        const int k = (blockIdx.x - NTOK / 256) * 256 + tid;   // 0..1023
        const float4* ep = (const float4*)(cb + (size_t)k * ED);
        const int m = k & 31, ct = k >> 5;
        float r[8];
#pragma unroll
        for (int g = 0; g < 8; ++g) {
            float4 a = ep[2 * g], b = ep[2 * g + 1];
            float v[8] = {a.x, a.y, a.z, a.w, b.x, b.y, b.z, b.w};
            short8 hv, lv;
#pragma unroll
            for (int j = 0; j < 8; ++j) {
                unsigned short hb = f2bf(v[j]);
                hv[j] = (short)hb;
                lv[j] = (short)f2bf(v[j] - bf2f(hb));
                const float sq = v[j] * v[j];          // frozen pairwise e_sq
                r[j] = g ? (r[j] + sq) : sq;
            }
            efH[(ct * 8 + g) * 32 + m] = hv;
            efL[(ct * 8 + g) * 32 + m] = lv;
        }
        e_sq[k] = ((r[0] + r[1]) + (r[2] + r[3])) + ((r[4] + r[5]) + (r[6] + r[7]));
        counts[k] = 0u;
        if (k == 0) *sse = 0.f;
    }
}

// ---------------------------------------------------------------------------
// phase 1: approx scores via bf16 MFMA (hh, h*l, l*h).
// Wave owns 64 codes (2 m-tiles, A-frags in regs); blockIdx.y = code group.
// Store per (token, 32-code tile): tA = -2*maxdot (low 5 mantissa bits =
// in-tile argmax row), tB = -2*secondmax.
// ---------------------------------------------------------------------------
__global__ __launch_bounds__(256, 2) void vq_approx(const short8* __restrict__ zfH,
                                                    const short8* __restrict__ zfL,
                                                    const short8* __restrict__ efH,
                                                    const short8* __restrict__ efL,
                                                    float* __restrict__ tA,
                                                    float* __restrict__ tB)
{
    const int tid = threadIdx.x;
    const int lane = tid & 63, wv = tid >> 6;
    const int h = lane >> 5, ml = lane & 31;
    const int ct0 = blockIdx.y * 8 + wv * 2;       // wave's two 32-code tiles

    short8 ea[2][4], eb[2][4];                     // A-frags: eh, el (in regs)
#pragma unroll
    for (int mt = 0; mt < 2; ++mt) {
        const int ct = ct0 + mt;
#pragma unroll
        for (int q = 0; q < 4; ++q) {
            const int idx = (ct * 8 + q * 2 + h) * 32 + ml;
            ea[mt][q] = efH[idx];
            eb[mt][q] = efL[idx];
        }
    }

    const int tt0 = blockIdx.x * 8;
    for (int it = 0; it < 8; ++it) {
        const int tt = tt0 + it;
        short8 zh[4], zl[4];
#pragma unroll
        for (int q = 0; q < 4; ++q) {
            const int idx = (tt * 8 + q * 2 + h) * 32 + ml;
            zh[q] = zfH[idx];
            zl[q] = zfL[idx];
        }
        float16 acc0 = {}, acc1 = {};
#pragma unroll
        for (int q = 0; q < 4; ++q) {
            acc0 = __builtin_amdgcn_mfma_f32_32x32x16_bf16(ea[0][q], zh[q], acc0, 0, 0, 0);
            acc1 = __builtin_amdgcn_mfma_f32_32x32x16_bf16(ea[1][q], zh[q], acc1, 0, 0, 0);
            acc0 = __builtin_amdgcn_mfma_f32_32x32x16_bf16(ea[0][q], zl[q], acc0, 0, 0, 0);
            acc1 = __builtin_amdgcn_mfma_f32_32x32x16_bf16(ea[1][q], zl[q], acc1, 0, 0, 0);
            acc0 = __builtin_amdgcn_mfma_f32_32x32x16_bf16(eb[0][q], zh[q], acc0, 0, 0, 0);
            acc1 = __builtin_amdgcn_mfma_f32_32x32x16_bf16(eb[1][q], zh[q], acc1, 0, 0, 0);
        }
#pragma unroll
        for (int mt = 0; mt < 2; ++mt) {
            const float16 acc = mt ? acc1 : acc0;
            float v1 = -FLT_MAX, v2 = -FLT_MAX;
            int i1 = 0;
#pragma unroll
            for (int rg = 0; rg < 16; ++rg) {
                const float v = acc[rg];
                const int mrow = (rg & 3) + 8 * (rg >> 2) + 4 * h;  // C/D row (m74/m101)
                if (v > v1) { v2 = v1; v1 = v; i1 = mrow; }
                else v2 = fmaxf(v2, v);
            }
            const float o1 = __shfl_xor(v1, 32);
            const float o2 = __shfl_xor(v2, 32);
            const int   oi = __shfl_xor(i1, 32);
            const float lo = fminf(v1, o1);
            if (o1 > v1) { v1 = o1; i1 = oi; }
            v2 = fmaxf(lo, fmaxf(v2, o2));          // exact 2nd-largest merge
            if (lane < 32) {
                const int t = tt * 32 + lane;        // C/D col = token
                const unsigned bits = (__float_as_uint(-2.f * v1) & ~31u) | (unsigned)i1;
                tA[(size_t)(ct0 + mt) * NTOK + t] = __uint_as_float(bits);
                tB[(size_t)(ct0 + mt) * NTOK + t] = -2.f * v2;
            }
        }
    }
}

// ---------------------------------------------------------------------------
// phase 2: candidate selection; exact rescore (frozen chain) ONLY for
// ambiguous tokens (~1-2%); fused epilogue. Divergent per-thread loops so
// masked lanes issue no gather traffic (round-6 fix: all-lane gathers were
// the 92us latency wall).
// ---------------------------------------------------------------------------
__global__ __launch_bounds__(256, 1) void vq_exact(const float* __restrict__ z_e,
                                                   const float* __restrict__ cb,
                                                   const float* __restrict__ e_sq,
                                                   const float* __restrict__ zsq_g,
                                                   const float* __restrict__ tA,
                                                   const float* __restrict__ tB,
                                                   float* __restrict__ out_zq,
                                                   float* __restrict__ out_idx,
                                                   unsigned int* __restrict__ counts,
                                                   float* __restrict__ sse)
{
#pragma clang fp contract(off)
    __shared__ unsigned int hist[K_CODES];
    __shared__ float wsum[4];
    const int tid = threadIdx.x;
    for (int i = tid; i < K_CODES; i += 256) hist[i] = 0u;
    __syncthreads();

    const int t = blockIdx.x * 256 + tid;

    // single pass over tA: buffer in regs, min
    float av[32];
    float m = FLT_MAX;
#pragma unroll
    for (int ct = 0; ct < 32; ++ct) {
        av[ct] = tA[(size_t)ct * NTOK + t];
        m = fminf(m, av[ct]);
    }
    const float thr = m + EPS;

    int cand[8];
    int cnt = 0;
    unsigned fullmask = 0;
#pragma unroll
    for (int ct = 0; ct < 32; ++ct) {
        if (av[ct] <= thr) {
            if (cnt < 8) cand[cnt++] = ct * 32 + (int)(__float_as_uint(av[ct]) & 31u);
            else fullmask |= (1u << ct);
            if (tB[(size_t)ct * NTOK + t] <= thr) fullmask |= (1u << ct);
        }
    }

    // z into regs (needed for SSE regardless)
    const float4* zp = (const float4*)(z_e + (size_t)t * ED);
    float zr[ED];
#pragma unroll
    for (int i = 0; i < 16; ++i) {
        float4 v = zp[i];
        zr[4 * i + 0] = v.x; zr[4 * i + 1] = v.y;
        zr[4 * i + 2] = v.z; zr[4 * i + 3] = v.w;
    }

    int bi;
    if (cnt == 1 && fullmask == 0u) {
        bi = cand[0];                   // unambiguous: band proves exact argmin
    } else {
        const float zsq = zsq_g[t];
        float best = FLT_MAX;
        bi = 0;
        for (int i = 0; i < cnt; ++i) {             // divergent per-thread loop
            const int c = cand[i];
            const float4* e4 = (const float4*)(cb + (size_t)c * ED);
            float eb[ED];
#pragma unroll
            for (int j = 0; j < 16; ++j) {
                float4 v = e4[j];
                eb[4 * j + 0] = v.x; eb[4 * j + 1] = v.y;
                eb[4 * j + 2] = v.z; eb[4 * j + 3] = v.w;
            }
            float a = 0.f;
#pragma unroll
            for (int d = 0; d < ED; ++d) a = fmaf(zr[d], eb[d], a);   // frozen
            const float d2 = fmaf(-2.f, a, zsq) + e_sq[c];
            if (d2 < best || (d2 == best && c < bi)) { best = d2; bi = c; }
        }
        while (fullmask) {                          // rare: ties / dense band
            const int ct = __ffs(fullmask) - 1;
            fullmask &= fullmask - 1;
            for (int j = 0; j < 32; ++j) {
                const int c = ct * 32 + j;
                const float4* e4 = (const float4*)(cb + (size_t)c * ED);
                float eb[ED];
#pragma unroll
                for (int jj = 0; jj < 16; ++jj) {
                    float4 v = e4[jj];
                    eb[4 * jj + 0] = v.x; eb[4 * jj + 1] = v.y;
                    eb[4 * jj + 2] = v.z; eb[4 * jj + 3] = v.w;
                }
                float a = 0.f;
#pragma unroll
                for (int d = 0; d < ED; ++d) a = fmaf(zr[d], eb[d], a);
                const float d2 = fmaf(-2.f, a, zsq) + e_sq[c];
                if (d2 < best || (d2 == best && c < bi)) { best = d2; bi = c; }
            }
        }
    }

    atomicAdd(&hist[bi], 1u);
    out_idx[t] = (float)bi;

    // gather selected code, write z_q, SSE (frozen fmaf chain, d order)
    const float4* eq = (const float4*)(cb + (size_t)bi * ED);
    float4* oz = (float4*)(out_zq + (size_t)t * ED);
    float lsse = 0.f;
#pragma unroll
    for (int i = 0; i < 16; ++i) {
        float4 q = eq[i];
        oz[i] = q;
        float dx = q.x - zr[4 * i + 0]; lsse = fmaf(dx, dx, lsse);
        float dy = q.y - zr[4 * i + 1]; lsse = fmaf(dy, dy, lsse);
        float dz = q.z - zr[4 * i + 2]; lsse = fmaf(dz, dz, lsse);
        float dw = q.w - zr[4 * i + 3]; lsse = fmaf(dw, dw, lsse);
    }
#pragma unroll
    for (int off = 32; off > 0; off >>= 1)
        lsse += __shfl_down(lsse, off, 64);
    const int lane = tid & 63, wid = tid >> 6;
    if (lane == 0) wsum[wid] = lsse;
    __syncthreads();
    if (tid == 0)
        atomicAdd(sse, (wsum[0] + wsum[1]) + (wsum[2] + wsum[3]));
    for (int i = tid; i < K_CODES; i += 256) {
        const unsigned int c = hist[i];
        if (c) atomicAdd(&counts[i], c);
    }
}

// ---------------------------------------------------------------------------
// final: entropy / losses scalars
// ---------------------------------------------------------------------------
__global__ __launch_bounds__(1024) void vq_final(const unsigned int* __restrict__ counts,
                                                 const float* __restrict__ sse,
                                                 float* __restrict__ out_sc)
{
    __shared__ float red[1024];
    const int i = threadIdx.x;
    const float c = (float)counts[i];
    const float p = c / (float)NTOK + 1e-10f;
    red[i] = p * logf(p);
    __syncthreads();
    for (int s = 512; s > 0; s >>= 1) {
        if (i < s) red[i] += red[i + s];
        __syncthreads();
    }
    if (i == 0) {
        const float entropy = -red[0];
        const float cbl = (*sse) / ((float)NTOK * (float)ED);
        out_sc[0] = cbl;                                   // codebook_loss
        out_sc[1] = 0.25f * cbl;                           // commitment_loss
        out_sc[2] = -0.1f * (entropy / 6.93147180559945f); // entropy_loss
        out_sc[3] = expf(entropy);                         // perplexity
    }
}

// ---------------------------------------------------------------------------
extern "C" void kernel_launch(void* const* d_in, const int* in_sizes, int n_in,
                              void* d_out, int out_size, void* d_ws, size_t ws_size,
                              hipStream_t stream)
{
    const float* z_e = (const float*)d_in[0];
    const float* cb  = (const float*)d_in[1];

    float* out   = (float*)d_out;
    float* o_zq  = out;                              // [131072,64]
    float* o_idx = out + (size_t)NTOK * ED;          // [131072] (as float)
    float* o_sc  = o_idx + NTOK;                     // 4 scalars

    char* ws = (char*)d_ws;
    float*        e_sq   = (float*)(ws);                     // 4 KB
    unsigned int* counts = (unsigned int*)(ws + 4096);       // 4 KB
    float*        sse    = (float*)(ws + 8192);              // 4 B
    float*        zsq_g  = (float*)(ws + 8448);              // 512 KB
    short8*       efH    = (short8*)(ws + 532736);           // 128 KB
    short8*       efL    = (short8*)(ws + 663808);           // 128 KB
    short8*       zfH    = (short8*)(ws + (1u << 20));       // 16 MB
    short8*       zfL    = (short8*)(ws + 17825792);         // 16 MB
    float*        tA     = (float*)(ws + 34603008);          // 16 MB
    float*        tB     = (float*)(ws + 51380224);          // 16 MB (end 64 MB)

    vq_pre   <<<NTOK / 256 + 4, 256, 0, stream>>>(z_e, cb, zsq_g, zfH, zfL,
                                                  e_sq, efH, efL, counts, sse);
    vq_approx<<<dim3(NTOK / 256, 4), 256, 0, stream>>>(zfH, zfL, efH, efL, tA, tB);
    vq_exact <<<NTOK / 256, 256, 0, stream>>>(z_e, cb, e_sq, zsq_g, tA, tB,
                                              o_zq, o_idx, counts, sse);
    vq_final <<<1, 1024, 0, stream>>>(counts, sse, o_sc);
}